// Round 8
// baseline (306.937 us; speedup 1.0000x reference)
//
#include <hip/hip_runtime.h>
#include <hip/hip_bf16.h>
#include <hip/hip_fp16.h>

// REGATConv on MI355X — round 8.
//   ws: fcb bf16[256*256] | ftb bf16[N*256] | el[N*4] | er[N*4] | offs[N+1] | cursor[N]
//       | rank int[E] | srcs_g int[E] | exq half4[E]
//   K1 memset cursor
//   K2 hist_cvt_rank: rank[i]=atomicAdd(cursor[dst[i]],1) + fc_w->bf16 convert
//   K3 single-block scan -> offs
//   K4 MFMA bf16 GEMM (32x256 tile, 1563 blocks, wave=head), fused el/er epilogue
//   K5 scatter4: p = offs[dst]+rank (NO atomic); srcs_g[p]=src, exq[p]=fp16x4 exp(leaky(...))
//   K6 agg2: one wave per dst node: seq exq sum -> 1/s, then 4x-unrolled ftb gather

#define NF 256
#define HD 256
#define NH 4

typedef __attribute__((ext_vector_type(8))) short short8;
typedef __attribute__((ext_vector_type(4))) float f32x4;

static __device__ __forceinline__ unsigned short f2bf(float f) {
  unsigned int u = __float_as_uint(f);
  u += 0x7FFFu + ((u >> 16) & 1u);   // RNE
  return (unsigned short)(u >> 16);
}
static __device__ __forceinline__ float bf2f(unsigned short s) {
  return __uint_as_float(((unsigned int)s) << 16);
}
static __device__ __forceinline__ unsigned pkbf(float a, float b) {
  __hip_bfloat162 h = __float22bfloat162_rn(make_float2(a, b));
  return *(unsigned*)&h;
}
static __device__ __forceinline__ unsigned pk2h(float a, float b) {
  __half2 h = __floats2half2_rn(a, b);   // low = a, high = b
  return *(unsigned*)&h;
}

// fused: dst histogram (stores per-edge rank) + fc_w fp32->bf16 convert
__global__ __launch_bounds__(256) void hist_cvt_rank_k(
    const int* __restrict__ dst, int* __restrict__ cursor,
    int* __restrict__ rank, const float* __restrict__ w,
    unsigned short* __restrict__ o, int e) {
  int i = blockIdx.x * 256 + threadIdx.x;
  if (i < 16384) {
    float4 v = ((const float4*)w)[i];
    ((uint2*)o)[i] = make_uint2(pkbf(v.x, v.y), pkbf(v.z, v.w));
  }
  if (i < e) rank[i] = atomicAdd(&cursor[dst[i]], 1);
}

// single-block scan, 1024 thr x 8 elem -> chunk 8192
__global__ __launch_bounds__(1024) void scan_k(const int* __restrict__ cursor,
                                               int* __restrict__ offs, int n) {
  __shared__ int wtot[16];
  __shared__ int wexcl[16];
  __shared__ int ctot;
  int tid = threadIdx.x, lane = tid & 63, wid = tid >> 6;
  int carry = 0;
  int nchunk = (n + 8191) >> 13;
  for (int c = 0; c < nchunk; ++c) {
    int base = (c << 13) + tid * 8;
    int v[8];
    if (base + 8 <= n) {
      int4 a = *(const int4*)(cursor + base);
      int4 b = *(const int4*)(cursor + base + 4);
      v[0] = a.x; v[1] = a.y; v[2] = a.z; v[3] = a.w;
      v[4] = b.x; v[5] = b.y; v[6] = b.z; v[7] = b.w;
    } else {
#pragma unroll
      for (int j = 0; j < 8; ++j) v[j] = (base + j < n) ? cursor[base + j] : 0;
    }
    int p[8]; int run = 0;
#pragma unroll
    for (int j = 0; j < 8; ++j) { run += v[j]; p[j] = run; }
    int incl = run;
#pragma unroll
    for (int off = 1; off < 64; off <<= 1) {
      int t = __shfl_up(incl, off);
      if (lane >= off) incl += t;
    }
    if (lane == 63) wtot[wid] = incl;
    __syncthreads();
    if (wid == 0 && lane < 16) {
      int wv = wtot[lane]; int wi = wv;
#pragma unroll
      for (int off = 1; off < 16; off <<= 1) {
        int t = __shfl_up(wi, off);
        if (lane >= off) wi += t;
      }
      wexcl[lane] = wi - wv;
      if (lane == 15) ctot = wi;
    }
    __syncthreads();
    int ebase = carry + wexcl[wid] + (incl - run);
#pragma unroll
    for (int j = 0; j < 8; ++j) {
      int i = base + j;
      if (i < n) offs[i] = ebase + p[j] - v[j];
    }
    carry += ctot;
    __syncthreads();
  }
  if (tid == 0) offs[n] = carry;
}

// MFMA GEMM: C[m][o] = sum_k feat[m][k]*fc_w[o][k]. Block: 32 rows x 256 cols,
// 4 waves; wave w owns cols [w*64, w*64+64) == head w. BK=64 (2 mfma k-steps).
// 1563 blocks (~6/CU) for latency hiding; acc[2][4] keeps VGPR low.
__global__ __launch_bounds__(256) void gemm_k(
    const float* __restrict__ feat, const unsigned short* __restrict__ fcb,
    const float* __restrict__ attn_l, const float* __restrict__ attn_r,
    unsigned short* __restrict__ ftb, float* __restrict__ el,
    float* __restrict__ er, int n) {
  __shared__ short aF[2 * 2 * 64 * 8];    // [rt(2)][s(2)][lane][8]  4 KB
  __shared__ short bF[16 * 2 * 64 * 8];   // [cg][s][lane][8] 32 KB
  int tid = threadIdx.x;
  int lane = tid & 63, w = tid >> 6;
  int row0 = blockIdx.x * 32;

  f32x4 acc[2][4];
#pragma unroll
  for (int i = 0; i < 2; ++i)
#pragma unroll
    for (int j = 0; j < 4; ++j) acc[i][j] = (f32x4){0.f, 0.f, 0.f, 0.f};

  // A staging: thread t -> row ar=t>>3 (0..31), k-octet ak=(t&7)*8
  int ar = tid >> 3, ak = (tid & 7) << 3;
  int arow = row0 + ar; if (arow >= n) arow = n - 1;
  const float* ap = feat + (size_t)arow * NF + ak;
  int am = ar & 15, art = ar >> 4;              // art 0..1
  int s0 = ak >> 5, q0 = (ak >> 3) & 3;
  short* aw0 = &aF[(((art * 2 + s0) * 64) + q0 * 16 + am) * 8];

  const unsigned short* bp = fcb + (size_t)tid * NF;
  int bn = tid & 15, bcg = tid >> 4;

  for (int k0 = 0; k0 < NF; k0 += 64) {
    float4 f0 = *(const float4*)(ap + k0);
    float4 f1 = *(const float4*)(ap + k0 + 4);
    uint4 oa = make_uint4(pkbf(f0.x, f0.y), pkbf(f0.z, f0.w),
                          pkbf(f1.x, f1.y), pkbf(f1.z, f1.w));
    *(uint4*)aw0 = oa;
#pragma unroll
    for (int o8 = 0; o8 < 8; ++o8) {
      short8 bv = *(const short8*)(bp + k0 + o8 * 8);
      int bs = o8 >> 2, bq = o8 & 3;
      *(short8*)&bF[(((bcg * 2 + bs) * 64) + bq * 16 + bn) * 8] = bv;
    }
    __syncthreads();
#pragma unroll
    for (int s = 0; s < 2; ++s) {
      short8 af[2], bfr[4];
#pragma unroll
      for (int rt = 0; rt < 2; ++rt)
        af[rt] = *(const short8*)&aF[(((rt * 2 + s) * 64) + lane) * 8];
#pragma unroll
      for (int ct = 0; ct < 4; ++ct)
        bfr[ct] = *(const short8*)&bF[((((w * 4 + ct) * 2 + s) * 64) + lane) * 8];
#pragma unroll
      for (int rt = 0; rt < 2; ++rt)
#pragma unroll
        for (int ct = 0; ct < 4; ++ct)
          acc[rt][ct] = __builtin_amdgcn_mfma_f32_16x16x32_bf16(
              af[rt], bfr[ct], acc[rt][ct], 0, 0, 0);
    }
    __syncthreads();
  }

  // epilogue: wave w == head w. C/D map: col = lane&15, row = (lane>>4)*4 + r.
  int ln = lane & 15, lq = lane >> 4;
  float al4[4], ar4[4];
#pragma unroll
  for (int ct = 0; ct < 4; ++ct) {
    al4[ct] = attn_l[w * 64 + ct * 16 + ln];
    ar4[ct] = attn_r[w * 64 + ct * 16 + ln];
  }
#pragma unroll
  for (int rt = 0; rt < 2; ++rt) {
#pragma unroll
    for (int r = 0; r < 4; ++r) {
      float pl = 0.f, pr = 0.f;
#pragma unroll
      for (int ct = 0; ct < 4; ++ct) {
        float v = acc[rt][ct][r];
        pl += v * al4[ct]; pr += v * ar4[ct];
      }
#pragma unroll
      for (int off = 1; off <= 8; off <<= 1) {
        pl += __shfl_xor(pl, off);
        pr += __shfl_xor(pr, off);
      }
      int row = row0 + rt * 16 + lq * 4 + r;
      if (row < n) {
        if (ln == 0) { el[row * NH + w] = pl; er[row * NH + w] = pr; }
        unsigned short* fr = ftb + (size_t)row * HD + w * 64 + ln;
#pragma unroll
        for (int ct = 0; ct < 4; ++ct) fr[ct * 16] = f2bf(acc[rt][ct][r]);
      }
    }
  }
}

// group edges by dst via p = offs[dst] + rank (NO atomics); exq packed fp16x4 (8B)
__global__ __launch_bounds__(256) void scatter4_k(
    const int* __restrict__ src, const int* __restrict__ dst,
    const int* __restrict__ efeats, const int* __restrict__ rank,
    const int* __restrict__ offs, const float* __restrict__ el,
    const float* __restrict__ er, const float* __restrict__ ewt,
    int* __restrict__ srcs_g, uint2* __restrict__ exq, int e) {
  __shared__ float ew_s[32];
  if (threadIdx.x < 32) {
    float v = ewt[threadIdx.x] * 100.0f;
    ew_s[threadIdx.x] = (v >= 0.f) ? v : 0.01f * v;
  }
  __syncthreads();
  int i = blockIdx.x * 256 + threadIdx.x;
  if (i >= e) return;
  int d = dst[i], s = src[i], t = efeats[i] - 1;
  int p = offs[d] + rank[i];
  float4 elv = *(const float4*)(el + (size_t)s * 4);
  float4 erv = *(const float4*)(er + (size_t)d * 4);
  const float* ew = &ew_s[t * 4];
  float x0 = (elv.x + erv.x) * ew[0]; x0 = (x0 >= 0.f) ? x0 : 0.2f * x0;
  float x1 = (elv.y + erv.y) * ew[1]; x1 = (x1 >= 0.f) ? x1 : 0.2f * x1;
  float x2 = (elv.z + erv.z) * ew[2]; x2 = (x2 >= 0.f) ? x2 : 0.2f * x2;
  float x3 = (elv.w + erv.w) * ew[3]; x3 = (x3 >= 0.f) ? x3 : 0.2f * x3;
  exq[p] = make_uint2(pk2h(__expf(x0), __expf(x1)), pk2h(__expf(x2), __expf(x3)));
  srcs_g[p] = s;
}

// one wave per dst node; lane owns output cols lane*4..lane*4+3 (head hl=lane>>4).
__global__ __launch_bounds__(256) void agg2_k(
    const unsigned short* __restrict__ ftb, const int* __restrict__ srcs_g,
    const uint2* __restrict__ exq, const int* __restrict__ offs,
    float* __restrict__ out, int n) {
  int node = blockIdx.x * 4 + (threadIdx.x >> 6);
  int lane = threadIdx.x & 63;
  if (node >= n) return;
  int start = offs[node];
  int deg = offs[node + 1] - start;
  float o0 = 0.f, o1 = 0.f, o2 = 0.f, o3 = 0.f;
  if (deg > 0) {
    // pass A: sequential sum of exq over the group (coalesced 8B loads)
    float s0 = 0.f, s1 = 0.f, s2 = 0.f, s3 = 0.f;
    for (int i = lane; i < deg; i += 64) {
      uint2 q = exq[(size_t)start + i];
      float2 f01 = __half22float2(*(__half2*)&q.x);
      float2 f23 = __half22float2(*(__half2*)&q.y);
      s0 += f01.x; s1 += f01.y; s2 += f23.x; s3 += f23.y;
    }
#pragma unroll
    for (int off = 1; off < 64; off <<= 1) {
      s0 += __shfl_xor(s0, off);
      s1 += __shfl_xor(s1, off);
      s2 += __shfl_xor(s2, off);
      s3 += __shfl_xor(s3, off);
    }
    int hl = lane >> 4;
    float sh = (hl == 0) ? s0 : (hl == 1) ? s1 : (hl == 2) ? s2 : s3;
    float rs = 1.0f / sh;
    // pass C: 4x-unrolled gather (4 outstanding 8B loads/lane)
    const __half* exs = (const __half*)exq;
    const unsigned short* fb = ftb + (size_t)lane * 4;
    const int* sg = srcs_g + start;
    long b4 = (long)start * 4 + hl;
    int i = 0;
    for (; i + 4 <= deg; i += 4) {
      int sA = sg[i], sB = sg[i + 1], sC = sg[i + 2], sD = sg[i + 3];
      float wA = __half2float(exs[b4 + (long)i * 4])       * rs;
      float wB = __half2float(exs[b4 + (long)(i + 1) * 4]) * rs;
      float wC = __half2float(exs[b4 + (long)(i + 2) * 4]) * rs;
      float wD = __half2float(exs[b4 + (long)(i + 3) * 4]) * rs;
      ushort4 fA = *(const ushort4*)(fb + (size_t)sA * HD);
      ushort4 fB = *(const ushort4*)(fb + (size_t)sB * HD);
      ushort4 fC = *(const ushort4*)(fb + (size_t)sC * HD);
      ushort4 fD = *(const ushort4*)(fb + (size_t)sD * HD);
      o0 = fmaf(wA, bf2f(fA.x), o0); o1 = fmaf(wA, bf2f(fA.y), o1);
      o2 = fmaf(wA, bf2f(fA.z), o2); o3 = fmaf(wA, bf2f(fA.w), o3);
      o0 = fmaf(wB, bf2f(fB.x), o0); o1 = fmaf(wB, bf2f(fB.y), o1);
      o2 = fmaf(wB, bf2f(fB.z), o2); o3 = fmaf(wB, bf2f(fB.w), o3);
      o0 = fmaf(wC, bf2f(fC.x), o0); o1 = fmaf(wC, bf2f(fC.y), o1);
      o2 = fmaf(wC, bf2f(fC.z), o2); o3 = fmaf(wC, bf2f(fC.w), o3);
      o0 = fmaf(wD, bf2f(fD.x), o0); o1 = fmaf(wD, bf2f(fD.y), o1);
      o2 = fmaf(wD, bf2f(fD.z), o2); o3 = fmaf(wD, bf2f(fD.w), o3);
    }
    for (; i < deg; ++i) {
      int sA = sg[i];
      float wA = __half2float(exs[b4 + (long)i * 4]) * rs;
      ushort4 fA = *(const ushort4*)(fb + (size_t)sA * HD);
      o0 = fmaf(wA, bf2f(fA.x), o0); o1 = fmaf(wA, bf2f(fA.y), o1);
      o2 = fmaf(wA, bf2f(fA.z), o2); o3 = fmaf(wA, bf2f(fA.w), o3);
    }
  }
  *(float4*)(out + (size_t)node * HD + lane * 4) = make_float4(o0, o1, o2, o3);
}

extern "C" void kernel_launch(void* const* d_in, const int* in_sizes, int n_in,
                              void* d_out, int out_size, void* d_ws, size_t ws_size,
                              hipStream_t stream) {
  const float* feat   = (const float*)d_in[0];
  const int*   src    = (const int*)d_in[1];
  const int*   dst    = (const int*)d_in[2];
  const int*   efeats = (const int*)d_in[3];
  const float* fc_w   = (const float*)d_in[4];
  const float* attn_l = (const float*)d_in[5];
  const float* attn_r = (const float*)d_in[6];
  const float* ewt    = (const float*)d_in[7];
  float* out = (float*)d_out;

  int N = in_sizes[0] / NF;   // 50000
  int E = in_sizes[1];        // 800000

  char* ws = (char*)d_ws;
  size_t off = 0;
  unsigned short* fcb = (unsigned short*)(ws + off); off += (size_t)NF * HD * 2;  // 128 KB
  unsigned short* ftb = (unsigned short*)(ws + off); off += (size_t)N * HD * 2;   // 25.6 MB
  float* el  = (float*)(ws + off);  off += (size_t)N * NH * 4;
  float* er  = (float*)(ws + off);  off += (size_t)N * NH * 4;
  int* offs  = (int*)(ws + off);    off += ((size_t)N + 16) * 4;
  int* cursor = (int*)(ws + off);   off += (size_t)N * 4;
  int* rank  = (int*)(ws + off);    off += (size_t)E * 4;                          // 3.2 MB
  int* srcs_g = (int*)(ws + off);   off += (size_t)E * 4;                          // 3.2 MB
  uint2* exq = (uint2*)(ws + off);  off += (size_t)E * 8;                          // 6.4 MB

  hipMemsetAsync(cursor, 0, (size_t)N * 4, stream);
  hist_cvt_rank_k<<<(E + 255) / 256, 256, 0, stream>>>(dst, cursor, rank, fc_w, fcb, E);
  scan_k<<<1, 1024, 0, stream>>>(cursor, offs, N);
  gemm_k<<<(N + 31) / 32, 256, 0, stream>>>(feat, fcb, attn_l, attn_r, ftb, el, er, N);
  scatter4_k<<<(E + 255) / 256, 256, 0, stream>>>(src, dst, efeats, rank, offs,
                                                  el, er, ewt, srcs_g, exq, E);
  agg2_k<<<(N + 3) / 4, 256, 0, stream>>>(ftb, srcs_g, exq, offs, out, N);
}